// Round 5
// baseline (274.231 us; speedup 1.0000x reference)
//
#include <hip/hip_runtime.h>
#include <hip/hip_bf16.h>

#define N_NODES 50000
#define N_EDGES 600000
#define IN_F 256
#define OUT_F 128
#define SCAN_BLOCKS 196   // ceil(50000/256)
#define LDS_K (IN_F + 8)  // +8 bf16 (16B) row pad: b128 frag reads hit all 8 bank-groups

typedef __bf16 bf16x8 __attribute__((ext_vector_type(8)));
typedef __bf16 bf16x2 __attribute__((ext_vector_type(2)));
typedef float  f32x4  __attribute__((ext_vector_type(4)));

// ---------------------------------------------------------------------------
// Kernel 0 (fused prep): wt[n][k] = bf16(W[k][n])  +  counts[] = 0
// ---------------------------------------------------------------------------
__global__ __launch_bounds__(256) void gcn_prep(const float* __restrict__ w,
                                                __bf16* __restrict__ wt,
                                                int* __restrict__ counts) {
    int i = blockIdx.x * 256 + threadIdx.x;
    if (i < N_NODES) counts[i] = 0;
    if (i < IN_F * OUT_F) {
        int k = i >> 7;          // consecutive i -> consecutive n: coalesced w read
        int n = i & 127;
        wt[n * IN_F + k] = (__bf16)w[i];
    }
}

// ---------------------------------------------------------------------------
// Kernel 1: support = bf16(x @ W) via MFMA 16x16x32.
// Block = 4 waves; wt staged in padded LDS (66 KB); each wave owns 2 m-tiles
// (32 rows); block covers 128 rows; grid covers all 50000 rows in one pass.
// ---------------------------------------------------------------------------
__global__ __launch_bounds__(256) void gcn_gemm_mfma(const float* __restrict__ x,
                                                     const __bf16* __restrict__ wt,
                                                     __bf16* __restrict__ support) {
    __shared__ __bf16 bs[OUT_F * LDS_K];   // 128 * 264 * 2 B = 66 KB

    const int t = threadIdx.x;
    // ---- stage wt -> LDS (coalesced 16B chunks; 16 chunks per thread) ----
#pragma unroll
    for (int i = 0; i < 16; i++) {
        int c  = i * 256 + t;        // chunk id 0..4095 (32 chunks of bf16x8 per n-row)
        int n  = c >> 5;
        int kc = c & 31;
        *(bf16x8*)&bs[n * LDS_K + kc * 8] = *(const bf16x8*)&wt[n * IN_F + kc * 8];
    }
    __syncthreads();

    const int wave = t >> 6;
    const int lane = t & 63;
    const int m    = lane & 15;
    const int quad = lane >> 4;
    const int row0 = blockIdx.x * 128 + wave * 32;   // this wave: rows row0..row0+31

    int r0 = row0 + m;
    int r1 = row0 + 16 + m;
    const float* xp0 = x + (size_t)(r0 < N_NODES ? r0 : 0) * IN_F + quad * 8;
    const float* xp1 = x + (size_t)(r1 < N_NODES ? r1 : 0) * IN_F + quad * 8;

    f32x4 acc0[8], acc1[8];
#pragma unroll
    for (int nt = 0; nt < 8; nt++) {
        acc0[nt] = (f32x4){0.f, 0.f, 0.f, 0.f};
        acc1[nt] = (f32x4){0.f, 0.f, 0.f, 0.f};
    }

#pragma unroll
    for (int ks = 0; ks < 8; ks++) {
        float4 a00 = *(const float4*)(xp0 + ks * 32);
        float4 a01 = *(const float4*)(xp0 + ks * 32 + 4);
        float4 a10 = *(const float4*)(xp1 + ks * 32);
        float4 a11 = *(const float4*)(xp1 + ks * 32 + 4);
        bf16x8 af0 = { (__bf16)a00.x, (__bf16)a00.y, (__bf16)a00.z, (__bf16)a00.w,
                       (__bf16)a01.x, (__bf16)a01.y, (__bf16)a01.z, (__bf16)a01.w };
        bf16x8 af1 = { (__bf16)a10.x, (__bf16)a10.y, (__bf16)a10.z, (__bf16)a10.w,
                       (__bf16)a11.x, (__bf16)a11.y, (__bf16)a11.z, (__bf16)a11.w };
#pragma unroll
        for (int nt = 0; nt < 8; nt++) {
            bf16x8 bf = *(const bf16x8*)&bs[(nt * 16 + m) * LDS_K + ks * 32 + quad * 8];
            acc0[nt] = __builtin_amdgcn_mfma_f32_16x16x32_bf16(af0, bf, acc0[nt], 0, 0, 0);
            acc1[nt] = __builtin_amdgcn_mfma_f32_16x16x32_bf16(af1, bf, acc1[nt], 0, 0, 0);
        }
    }

    // C/D layout: col = lane&15, row = quad*4 + reg  [m89-verified]
#pragma unroll
    for (int nt = 0; nt < 8; nt++) {
#pragma unroll
        for (int r = 0; r < 4; r++) {
            int ra = row0 + quad * 4 + r;
            if (ra < N_NODES)
                support[(size_t)ra * OUT_F + nt * 16 + m] = (__bf16)acc0[nt][r];
            int rb = ra + 16;
            if (rb < N_NODES)
                support[(size_t)rb * OUT_F + nt * 16 + m] = (__bf16)acc1[nt][r];
        }
    }
}

// ---------------------------------------------------------------------------
// Kernel 2: histogram (+rank per edge)
// ---------------------------------------------------------------------------
__global__ __launch_bounds__(256) void gcn_hist(const int* __restrict__ erows,
                                                int* __restrict__ counts,
                                                int* __restrict__ rank) {
    int e = blockIdx.x * 256 + threadIdx.x;
    if (e < N_EDGES) rank[e] = atomicAdd(&counts[erows[e]], 1);
}

// ---------------------------------------------------------------------------
// Kernel 3 (fused scan): exclusive scan of counts -> row_start, ONE block.
// Phase A: per-thread chunk sum; Phase B: LDS block scan of 1024 sums;
// Phase C: per-thread prefix write-back.
// ---------------------------------------------------------------------------
#define SCAN_T 1024
#define SCAN_C 49   // ceil(50000/1024)

__global__ __launch_bounds__(SCAN_T) void gcn_scan(const int* __restrict__ counts,
                                                   int* __restrict__ row_start) {
    __shared__ int s[SCAN_T];
    const int t = threadIdx.x;
    const int base = t * SCAN_C;

    int sum = 0;
#pragma unroll 7
    for (int j = 0; j < SCAN_C; j++) {
        int i = base + j;
        if (i < N_NODES) sum += counts[i];
    }
    s[t] = sum;
    __syncthreads();
#pragma unroll
    for (int off = 1; off < SCAN_T; off <<= 1) {
        int v = (t >= off) ? s[t - off] : 0;
        __syncthreads();
        s[t] += v;
        __syncthreads();
    }
    int prefix = (t == 0) ? 0 : s[t - 1];   // exclusive prefix of this chunk
#pragma unroll 7
    for (int j = 0; j < SCAN_C; j++) {
        int i = base + j;
        if (i < N_NODES) {
            row_start[i] = prefix;
            prefix += counts[i];
        }
    }
    if (t == 0) row_start[N_NODES] = N_EDGES;
}

// ---------------------------------------------------------------------------
// Kernel 4: packed scatter into row-sorted edge list
// ---------------------------------------------------------------------------
__global__ __launch_bounds__(256) void gcn_scatter(const int* __restrict__ erows,
                                                   const int* __restrict__ ecols,
                                                   const float* __restrict__ evals,
                                                   const int* __restrict__ row_start,
                                                   const int* __restrict__ rank,
                                                   int2* __restrict__ sorted_cv) {
    int e = blockIdx.x * 256 + threadIdx.x;
    if (e < N_EDGES) {
        int pos = row_start[erows[e]] + rank[e];
        sorted_cv[pos] = make_int2(ecols[e], __float_as_int(evals[e]));
    }
}

// ---------------------------------------------------------------------------
// Kernel 5: aggregate. One wave per node; bf16x2/lane covers 128 cols.
// Unroll-4: all 4 cv loads + all 4 gathers issued before FMAs (MLP=4).
// out[n] = bias + sum_{e in row n} val_e * support[col_e]
// ---------------------------------------------------------------------------
__global__ __launch_bounds__(256) void gcn_aggregate_csr(const __bf16* __restrict__ support,
                                                         const int2* __restrict__ sorted_cv,
                                                         const int* __restrict__ row_start,
                                                         const float* __restrict__ bias,
                                                         float* __restrict__ out) {
    const int node = (blockIdx.x * 256 + threadIdx.x) >> 6;
    const int lane = threadIdx.x & 63;
    if (node >= N_NODES) return;

    const int beg = row_start[node];
    const int end = row_start[node + 1];

    float2 accA = *(const float2*)&bias[lane * 2];
    float2 accB = make_float2(0.f, 0.f);
    const __bf16* sp = support + lane * 2;

    int i = beg;
    for (; i + 3 < end; i += 4) {
        int2 cv0 = sorted_cv[i];
        int2 cv1 = sorted_cv[i + 1];
        int2 cv2 = sorted_cv[i + 2];
        int2 cv3 = sorted_cv[i + 3];
        bf16x2 s0 = *(const bf16x2*)(sp + (size_t)cv0.x * OUT_F);
        bf16x2 s1 = *(const bf16x2*)(sp + (size_t)cv1.x * OUT_F);
        bf16x2 s2 = *(const bf16x2*)(sp + (size_t)cv2.x * OUT_F);
        bf16x2 s3 = *(const bf16x2*)(sp + (size_t)cv3.x * OUT_F);
        float v0 = __int_as_float(cv0.y);
        float v1 = __int_as_float(cv1.y);
        float v2 = __int_as_float(cv2.y);
        float v3 = __int_as_float(cv3.y);
        accA.x += v0 * (float)s0.x + v1 * (float)s1.x;
        accA.y += v0 * (float)s0.y + v1 * (float)s1.y;
        accB.x += v2 * (float)s2.x + v3 * (float)s3.x;
        accB.y += v2 * (float)s2.y + v3 * (float)s3.y;
    }
    for (; i < end; i++) {
        int2 cv = sorted_cv[i];
        float v = __int_as_float(cv.y);
        bf16x2 s = *(const bf16x2*)(sp + (size_t)cv.x * OUT_F);
        accA.x += v * (float)s.x;
        accA.y += v * (float)s.y;
    }
    accA.x += accB.x;
    accA.y += accB.y;

    *(float2*)&out[(size_t)node * OUT_F + lane * 2] = accA;
}

// ---------------------------------------------------------------------------
static inline size_t align_up(size_t v, size_t a) { return (v + a - 1) & ~(a - 1); }

extern "C" void kernel_launch(void* const* d_in, const int* in_sizes, int n_in,
                              void* d_out, int out_size, void* d_ws, size_t ws_size,
                              hipStream_t stream) {
    const float* x     = (const float*)d_in[0];   // [50000, 256]
    const int*   erows = (const int*)d_in[1];     // [600000]
    const int*   ecols = (const int*)d_in[2];     // [600000]
    const float* evals = (const float*)d_in[3];   // [600000]
    const float* w     = (const float*)d_in[4];   // [256, 128]
    const float* bias  = (const float*)d_in[5];   // [128]
    float* out = (float*)d_out;                   // [50000, 128]

    // workspace layout (all regions 64B-aligned; ~20.7 MB total)
    size_t off = 0;
    __bf16* support   = (__bf16*)((char*)d_ws + off);
    off = align_up(off + (size_t)N_NODES * OUT_F * 2, 64);
    __bf16* wt        = (__bf16*)((char*)d_ws + off);
    off = align_up(off + (size_t)IN_F * OUT_F * 2, 64);
    int*    counts    = (int*)((char*)d_ws + off);
    off = align_up(off + (size_t)N_NODES * 4, 64);
    int*    row_start = (int*)((char*)d_ws + off);
    off = align_up(off + (size_t)(N_NODES + 1) * 4, 64);
    int*    rank      = (int*)((char*)d_ws + off);
    off = align_up(off + (size_t)N_EDGES * 4, 64);
    int2*   sorted_cv = (int2*)((char*)d_ws + off);

    const int eblocks = (N_EDGES + 255) / 256;

    // 1) prep: wt transpose + counts zero
    gcn_prep<<<SCAN_BLOCKS, 256, 0, stream>>>(w, wt, counts);

    // 2) GEMM: support = bf16(x @ W)
    gcn_gemm_mfma<<<(N_NODES + 127) / 128, 256, 0, stream>>>(x, wt, support);

    // 3) histogram + rank
    gcn_hist<<<eblocks, 256, 0, stream>>>(erows, counts, rank);

    // 4) fused exclusive scan (single block)
    gcn_scan<<<1, SCAN_T, 0, stream>>>(counts, row_start);

    // 5) scatter to row-sorted edge list
    gcn_scatter<<<eblocks, 256, 0, stream>>>(erows, ecols, evals, row_start, rank,
                                             sorted_cv);

    // 6) aggregate + bias (one wave per node, 4 nodes per block)
    gcn_aggregate_csr<<<(N_NODES + 3) / 4, 256, 0, stream>>>(
        support, sorted_cv, row_start, bias, out);
}

// Round 6
// 228.697 us; speedup vs baseline: 1.1991x; 1.1991x over previous
//
#include <hip/hip_runtime.h>
#include <hip/hip_bf16.h>

#define N_NODES 50000
#define N_EDGES 600000
#define IN_F 256
#define OUT_F 128
#define SCAN_BLOCKS 196   // ceil(50000/256)
#define LDS_K (IN_F + 8)  // +8 bf16 (16B) row pad: b128 frag reads hit all 8 bank-groups

typedef __bf16 bf16x8 __attribute__((ext_vector_type(8)));
typedef __bf16 bf16x2 __attribute__((ext_vector_type(2)));
typedef float  f32x4  __attribute__((ext_vector_type(4)));

// ---------------------------------------------------------------------------
// Kernel 0 (fused prep): wt[n][k] = bf16(W[k][n])  +  counts[] = 0
// ---------------------------------------------------------------------------
__global__ __launch_bounds__(256) void gcn_prep(const float* __restrict__ w,
                                                __bf16* __restrict__ wt,
                                                int* __restrict__ counts) {
    int i = blockIdx.x * 256 + threadIdx.x;
    if (i < N_NODES) counts[i] = 0;
    if (i < IN_F * OUT_F) {
        int k = i >> 7;          // consecutive i -> consecutive n: coalesced w read
        int n = i & 127;
        wt[n * IN_F + k] = (__bf16)w[i];
    }
}

// ---------------------------------------------------------------------------
// Kernel 1: support = bf16(x @ W) via MFMA 16x16x32.
// Block = 4 waves; wt staged in padded LDS (66 KB); each wave owns 2 m-tiles
// (32 rows); block covers 128 rows; grid covers all 50000 rows in one pass.
// ---------------------------------------------------------------------------
__global__ __launch_bounds__(256) void gcn_gemm_mfma(const float* __restrict__ x,
                                                     const __bf16* __restrict__ wt,
                                                     __bf16* __restrict__ support) {
    __shared__ __bf16 bs[OUT_F * LDS_K];   // 128 * 264 * 2 B = 66 KB

    const int t = threadIdx.x;
    // ---- stage wt -> LDS (coalesced 16B chunks; 16 chunks per thread) ----
#pragma unroll
    for (int i = 0; i < 16; i++) {
        int c  = i * 256 + t;        // chunk id 0..4095 (32 chunks of bf16x8 per n-row)
        int n  = c >> 5;
        int kc = c & 31;
        *(bf16x8*)&bs[n * LDS_K + kc * 8] = *(const bf16x8*)&wt[n * IN_F + kc * 8];
    }
    __syncthreads();

    const int wave = t >> 6;
    const int lane = t & 63;
    const int m    = lane & 15;
    const int quad = lane >> 4;
    const int row0 = blockIdx.x * 128 + wave * 32;   // this wave: rows row0..row0+31

    int r0 = row0 + m;
    int r1 = row0 + 16 + m;
    const float* xp0 = x + (size_t)(r0 < N_NODES ? r0 : 0) * IN_F + quad * 8;
    const float* xp1 = x + (size_t)(r1 < N_NODES ? r1 : 0) * IN_F + quad * 8;

    f32x4 acc0[8], acc1[8];
#pragma unroll
    for (int nt = 0; nt < 8; nt++) {
        acc0[nt] = (f32x4){0.f, 0.f, 0.f, 0.f};
        acc1[nt] = (f32x4){0.f, 0.f, 0.f, 0.f};
    }

#pragma unroll
    for (int ks = 0; ks < 8; ks++) {
        float4 a00 = *(const float4*)(xp0 + ks * 32);
        float4 a01 = *(const float4*)(xp0 + ks * 32 + 4);
        float4 a10 = *(const float4*)(xp1 + ks * 32);
        float4 a11 = *(const float4*)(xp1 + ks * 32 + 4);
        bf16x8 af0 = { (__bf16)a00.x, (__bf16)a00.y, (__bf16)a00.z, (__bf16)a00.w,
                       (__bf16)a01.x, (__bf16)a01.y, (__bf16)a01.z, (__bf16)a01.w };
        bf16x8 af1 = { (__bf16)a10.x, (__bf16)a10.y, (__bf16)a10.z, (__bf16)a10.w,
                       (__bf16)a11.x, (__bf16)a11.y, (__bf16)a11.z, (__bf16)a11.w };
#pragma unroll
        for (int nt = 0; nt < 8; nt++) {
            bf16x8 bf = *(const bf16x8*)&bs[(nt * 16 + m) * LDS_K + ks * 32 + quad * 8];
            acc0[nt] = __builtin_amdgcn_mfma_f32_16x16x32_bf16(af0, bf, acc0[nt], 0, 0, 0);
            acc1[nt] = __builtin_amdgcn_mfma_f32_16x16x32_bf16(af1, bf, acc1[nt], 0, 0, 0);
        }
    }

    // C/D layout: col = lane&15, row = quad*4 + reg  [m89-verified]
#pragma unroll
    for (int nt = 0; nt < 8; nt++) {
#pragma unroll
        for (int r = 0; r < 4; r++) {
            int ra = row0 + quad * 4 + r;
            if (ra < N_NODES)
                support[(size_t)ra * OUT_F + nt * 16 + m] = (__bf16)acc0[nt][r];
            int rb = ra + 16;
            if (rb < N_NODES)
                support[(size_t)rb * OUT_F + nt * 16 + m] = (__bf16)acc1[nt][r];
        }
    }
}

// ---------------------------------------------------------------------------
// Kernel 2: histogram (+rank per edge)
// ---------------------------------------------------------------------------
__global__ __launch_bounds__(256) void gcn_hist(const int* __restrict__ erows,
                                                int* __restrict__ counts,
                                                int* __restrict__ rank) {
    int e = blockIdx.x * 256 + threadIdx.x;
    if (e < N_EDGES) rank[e] = atomicAdd(&counts[erows[e]], 1);
}

// ---------------------------------------------------------------------------
// Kernel 3: single-block exclusive scan, wave-parallel + coalesced.
// 16 waves x contiguous 3125-node spans; per iter: coalesced 64-wide load ->
// shfl inclusive wave-scan -> store exclusive + carry. Cross-wave fixup via
// LDS, then coalesced add-back. No dependent global load chains.
// ---------------------------------------------------------------------------
#define SCAN_WAVES 16
#define SPAN 3125   // ceil(50000/16)

__global__ __launch_bounds__(1024) void gcn_scan(const int* __restrict__ counts,
                                                 int* __restrict__ row_start) {
    __shared__ int wtot[SCAN_WAVES];
    __shared__ int wpre[SCAN_WAVES];
    const int t = threadIdx.x;
    const int w = t >> 6;
    const int lane = t & 63;
    const int sbeg = w * SPAN;
    const int send = min(sbeg + SPAN, N_NODES);

    int carry = 0;
    for (int base = sbeg; base < sbeg + SPAN; base += 64) {
        int i = base + lane;
        int v = (i < send) ? counts[i] : 0;
        int incl = v;
#pragma unroll
        for (int off = 1; off < 64; off <<= 1) {
            int u = __shfl_up(incl, off, 64);
            if (lane >= off) incl += u;
        }
        if (i < send) row_start[i] = carry + incl - v;   // exclusive within span
        carry += __shfl(incl, 63, 64);
    }
    if (lane == 0) wtot[w] = carry;
    __syncthreads();
    if (t == 0) {
        int acc = 0;
#pragma unroll
        for (int j = 0; j < SCAN_WAVES; j++) { wpre[j] = acc; acc += wtot[j]; }
    }
    __syncthreads();
    const int add = wpre[w];
    if (add != 0) {                                       // wave-uniform branch
        for (int base = sbeg; base < sbeg + SPAN; base += 64) {
            int i = base + lane;
            if (i < send) row_start[i] += add;
        }
    }
    if (t == 0) row_start[N_NODES] = N_EDGES;
}

// ---------------------------------------------------------------------------
// Kernel 4: packed scatter into row-sorted edge list
// ---------------------------------------------------------------------------
__global__ __launch_bounds__(256) void gcn_scatter(const int* __restrict__ erows,
                                                   const int* __restrict__ ecols,
                                                   const float* __restrict__ evals,
                                                   const int* __restrict__ row_start,
                                                   const int* __restrict__ rank,
                                                   int2* __restrict__ sorted_cv) {
    int e = blockIdx.x * 256 + threadIdx.x;
    if (e < N_EDGES) {
        int pos = row_start[erows[e]] + rank[e];
        sorted_cv[pos] = make_int2(ecols[e], __float_as_int(evals[e]));
    }
}

// ---------------------------------------------------------------------------
// Kernel 5: aggregate. One wave per node; bf16x2/lane covers 128 cols.
// Unroll-4: all 4 cv loads + all 4 gathers issued before FMAs (MLP=4).
// out[n] = bias + sum_{e in row n} val_e * support[col_e]
// ---------------------------------------------------------------------------
__global__ __launch_bounds__(256) void gcn_aggregate_csr(const __bf16* __restrict__ support,
                                                         const int2* __restrict__ sorted_cv,
                                                         const int* __restrict__ row_start,
                                                         const float* __restrict__ bias,
                                                         float* __restrict__ out) {
    const int node = (blockIdx.x * 256 + threadIdx.x) >> 6;
    const int lane = threadIdx.x & 63;
    if (node >= N_NODES) return;

    const int beg = row_start[node];
    const int end = row_start[node + 1];

    float2 accA = *(const float2*)&bias[lane * 2];
    float2 accB = make_float2(0.f, 0.f);
    const __bf16* sp = support + lane * 2;

    int i = beg;
    for (; i + 3 < end; i += 4) {
        int2 cv0 = sorted_cv[i];
        int2 cv1 = sorted_cv[i + 1];
        int2 cv2 = sorted_cv[i + 2];
        int2 cv3 = sorted_cv[i + 3];
        bf16x2 s0 = *(const bf16x2*)(sp + (size_t)cv0.x * OUT_F);
        bf16x2 s1 = *(const bf16x2*)(sp + (size_t)cv1.x * OUT_F);
        bf16x2 s2 = *(const bf16x2*)(sp + (size_t)cv2.x * OUT_F);
        bf16x2 s3 = *(const bf16x2*)(sp + (size_t)cv3.x * OUT_F);
        float v0 = __int_as_float(cv0.y);
        float v1 = __int_as_float(cv1.y);
        float v2 = __int_as_float(cv2.y);
        float v3 = __int_as_float(cv3.y);
        accA.x += v0 * (float)s0.x + v1 * (float)s1.x;
        accA.y += v0 * (float)s0.y + v1 * (float)s1.y;
        accB.x += v2 * (float)s2.x + v3 * (float)s3.x;
        accB.y += v2 * (float)s2.y + v3 * (float)s3.y;
    }
    for (; i < end; i++) {
        int2 cv = sorted_cv[i];
        float v = __int_as_float(cv.y);
        bf16x2 s = *(const bf16x2*)(sp + (size_t)cv.x * OUT_F);
        accA.x += v * (float)s.x;
        accA.y += v * (float)s.y;
    }
    accA.x += accB.x;
    accA.y += accB.y;

    *(float2*)&out[(size_t)node * OUT_F + lane * 2] = accA;
}

// ---------------------------------------------------------------------------
static inline size_t align_up(size_t v, size_t a) { return (v + a - 1) & ~(a - 1); }

extern "C" void kernel_launch(void* const* d_in, const int* in_sizes, int n_in,
                              void* d_out, int out_size, void* d_ws, size_t ws_size,
                              hipStream_t stream) {
    const float* x     = (const float*)d_in[0];   // [50000, 256]
    const int*   erows = (const int*)d_in[1];     // [600000]
    const int*   ecols = (const int*)d_in[2];     // [600000]
    const float* evals = (const float*)d_in[3];   // [600000]
    const float* w     = (const float*)d_in[4];   // [256, 128]
    const float* bias  = (const float*)d_in[5];   // [128]
    float* out = (float*)d_out;                   // [50000, 128]

    // workspace layout (all regions 64B-aligned; ~20.7 MB total)
    size_t off = 0;
    __bf16* support   = (__bf16*)((char*)d_ws + off);
    off = align_up(off + (size_t)N_NODES * OUT_F * 2, 64);
    __bf16* wt        = (__bf16*)((char*)d_ws + off);
    off = align_up(off + (size_t)IN_F * OUT_F * 2, 64);
    int*    counts    = (int*)((char*)d_ws + off);
    off = align_up(off + (size_t)N_NODES * 4, 64);
    int*    row_start = (int*)((char*)d_ws + off);
    off = align_up(off + (size_t)(N_NODES + 1) * 4, 64);
    int*    rank      = (int*)((char*)d_ws + off);
    off = align_up(off + (size_t)N_EDGES * 4, 64);
    int2*   sorted_cv = (int2*)((char*)d_ws + off);

    const int eblocks = (N_EDGES + 255) / 256;

    // 1) prep: wt transpose + counts zero
    gcn_prep<<<SCAN_BLOCKS, 256, 0, stream>>>(w, wt, counts);

    // 2) GEMM: support = bf16(x @ W)
    gcn_gemm_mfma<<<(N_NODES + 127) / 128, 256, 0, stream>>>(x, wt, support);

    // 3) histogram + rank
    gcn_hist<<<eblocks, 256, 0, stream>>>(erows, counts, rank);

    // 4) exclusive scan (single block, wave-parallel, coalesced)
    gcn_scan<<<1, 1024, 0, stream>>>(counts, row_start);

    // 5) scatter to row-sorted edge list
    gcn_scatter<<<eblocks, 256, 0, stream>>>(erows, ecols, evals, row_start, rank,
                                             sorted_cv);

    // 6) aggregate + bias (one wave per node, 4 nodes per block)
    gcn_aggregate_csr<<<(N_NODES + 3) / 4, 256, 0, stream>>>(
        support, sorted_cv, row_start, bias, out);
}

// Round 7
// 192.140 us; speedup vs baseline: 1.4272x; 1.1903x over previous
//
#include <hip/hip_runtime.h>
#include <hip/hip_bf16.h>

#define N_NODES 50000
#define N_EDGES 600000
#define IN_F 256
#define OUT_F 128
#define SCAN_BLOCKS 196   // ceil(50000/256)
#define LDS_K (IN_F + 8)  // +8 bf16 (16B) row pad: b128 frag reads hit all 8 bank-groups

typedef __bf16 bf16x8 __attribute__((ext_vector_type(8)));
typedef __bf16 bf16x2 __attribute__((ext_vector_type(2)));
typedef float  f32x4  __attribute__((ext_vector_type(4)));

// ---------------------------------------------------------------------------
// Kernel 0 (fused prep): wt[n][k] = bf16(W[k][n])  +  counts[] = 0
// ---------------------------------------------------------------------------
__global__ __launch_bounds__(256) void gcn_prep(const float* __restrict__ w,
                                                __bf16* __restrict__ wt,
                                                int* __restrict__ counts) {
    int i = blockIdx.x * 256 + threadIdx.x;
    if (i < N_NODES) counts[i] = 0;
    if (i < IN_F * OUT_F) {
        int k = i >> 7;          // consecutive i -> consecutive n: coalesced w read
        int n = i & 127;
        wt[n * IN_F + k] = (__bf16)w[i];
    }
}

// ---------------------------------------------------------------------------
// Kernel 1: support = bf16(x @ W) via MFMA 16x16x32.
// Block = 4 waves; wt staged in padded LDS (66 KB); each wave owns 2 m-tiles
// (32 rows); block covers 128 rows; grid covers all 50000 rows in one pass.
// ---------------------------------------------------------------------------
__global__ __launch_bounds__(256) void gcn_gemm_mfma(const float* __restrict__ x,
                                                     const __bf16* __restrict__ wt,
                                                     __bf16* __restrict__ support) {
    __shared__ __bf16 bs[OUT_F * LDS_K];   // 128 * 264 * 2 B = 66 KB

    const int t = threadIdx.x;
    // ---- stage wt -> LDS (coalesced 16B chunks; 16 chunks per thread) ----
#pragma unroll
    for (int i = 0; i < 16; i++) {
        int c  = i * 256 + t;        // chunk id 0..4095 (32 chunks of bf16x8 per n-row)
        int n  = c >> 5;
        int kc = c & 31;
        *(bf16x8*)&bs[n * LDS_K + kc * 8] = *(const bf16x8*)&wt[n * IN_F + kc * 8];
    }
    __syncthreads();

    const int wave = t >> 6;
    const int lane = t & 63;
    const int m    = lane & 15;
    const int quad = lane >> 4;
    const int row0 = blockIdx.x * 128 + wave * 32;   // this wave: rows row0..row0+31

    int r0 = row0 + m;
    int r1 = row0 + 16 + m;
    const float* xp0 = x + (size_t)(r0 < N_NODES ? r0 : 0) * IN_F + quad * 8;
    const float* xp1 = x + (size_t)(r1 < N_NODES ? r1 : 0) * IN_F + quad * 8;

    f32x4 acc0[8], acc1[8];
#pragma unroll
    for (int nt = 0; nt < 8; nt++) {
        acc0[nt] = (f32x4){0.f, 0.f, 0.f, 0.f};
        acc1[nt] = (f32x4){0.f, 0.f, 0.f, 0.f};
    }

#pragma unroll
    for (int ks = 0; ks < 8; ks++) {
        float4 a00 = *(const float4*)(xp0 + ks * 32);
        float4 a01 = *(const float4*)(xp0 + ks * 32 + 4);
        float4 a10 = *(const float4*)(xp1 + ks * 32);
        float4 a11 = *(const float4*)(xp1 + ks * 32 + 4);
        bf16x8 af0 = { (__bf16)a00.x, (__bf16)a00.y, (__bf16)a00.z, (__bf16)a00.w,
                       (__bf16)a01.x, (__bf16)a01.y, (__bf16)a01.z, (__bf16)a01.w };
        bf16x8 af1 = { (__bf16)a10.x, (__bf16)a10.y, (__bf16)a10.z, (__bf16)a10.w,
                       (__bf16)a11.x, (__bf16)a11.y, (__bf16)a11.z, (__bf16)a11.w };
#pragma unroll
        for (int nt = 0; nt < 8; nt++) {
            bf16x8 bf = *(const bf16x8*)&bs[(nt * 16 + m) * LDS_K + ks * 32 + quad * 8];
            acc0[nt] = __builtin_amdgcn_mfma_f32_16x16x32_bf16(af0, bf, acc0[nt], 0, 0, 0);
            acc1[nt] = __builtin_amdgcn_mfma_f32_16x16x32_bf16(af1, bf, acc1[nt], 0, 0, 0);
        }
    }

    // C/D layout: col = lane&15, row = quad*4 + reg  [m89-verified]
#pragma unroll
    for (int nt = 0; nt < 8; nt++) {
#pragma unroll
        for (int r = 0; r < 4; r++) {
            int ra = row0 + quad * 4 + r;
            if (ra < N_NODES)
                support[(size_t)ra * OUT_F + nt * 16 + m] = (__bf16)acc0[nt][r];
            int rb = ra + 16;
            if (rb < N_NODES)
                support[(size_t)rb * OUT_F + nt * 16 + m] = (__bf16)acc1[nt][r];
        }
    }
}

// ---------------------------------------------------------------------------
// Kernel 2: histogram (+rank per edge)
// ---------------------------------------------------------------------------
__global__ __launch_bounds__(256) void gcn_hist(const int* __restrict__ erows,
                                                int* __restrict__ counts,
                                                int* __restrict__ rank) {
    int e = blockIdx.x * 256 + threadIdx.x;
    if (e < N_EDGES) rank[e] = atomicAdd(&counts[erows[e]], 1);
}

// ---------------------------------------------------------------------------
// Kernel 3: per-block exclusive scan of counts (196 blocks) -> partials
// ---------------------------------------------------------------------------
__global__ __launch_bounds__(256) void gcn_scan1(const int* __restrict__ counts,
                                                 int* __restrict__ row_start,
                                                 int* __restrict__ partials) {
    __shared__ int s[256];
    const int t = threadIdx.x;
    const int i = blockIdx.x * 256 + t;
    int v = (i < N_NODES) ? counts[i] : 0;
    s[t] = v;
    __syncthreads();
#pragma unroll
    for (int off = 1; off < 256; off <<= 1) {
        int x = (t >= off) ? s[t - off] : 0;
        __syncthreads();
        s[t] += x;
        __syncthreads();
    }
    if (i < N_NODES) row_start[i] = s[t] - v;
    if (t == 255) partials[blockIdx.x] = s[255];
}

// ---------------------------------------------------------------------------
// Kernel 4: fixup (196 blocks). Every block redundantly scans the 196-entry
// partials array in LDS (L2-hot, cheap), then adds its exclusive block-prefix
// to its 256 row_start entries. Full-GPU parallel, no serial chains.
// ---------------------------------------------------------------------------
__global__ __launch_bounds__(256) void gcn_scan_fixup(int* __restrict__ row_start,
                                                      const int* __restrict__ partials) {
    __shared__ int s[256];
    const int t = threadIdx.x;
    int v = (t < SCAN_BLOCKS) ? partials[t] : 0;
    s[t] = v;
    __syncthreads();
#pragma unroll
    for (int off = 1; off < 256; off <<= 1) {
        int x = (t >= off) ? s[t - off] : 0;
        __syncthreads();
        s[t] += x;
        __syncthreads();
    }
    const int add = (blockIdx.x == 0) ? 0 : s[blockIdx.x - 1];
    const int i = blockIdx.x * 256 + t;
    if (i < N_NODES) row_start[i] += add;
    if (i == 0) row_start[N_NODES] = N_EDGES;
}

// ---------------------------------------------------------------------------
// Kernel 5: packed scatter into row-sorted edge list
// ---------------------------------------------------------------------------
__global__ __launch_bounds__(256) void gcn_scatter(const int* __restrict__ erows,
                                                   const int* __restrict__ ecols,
                                                   const float* __restrict__ evals,
                                                   const int* __restrict__ row_start,
                                                   const int* __restrict__ rank,
                                                   int2* __restrict__ sorted_cv) {
    int e = blockIdx.x * 256 + threadIdx.x;
    if (e < N_EDGES) {
        int pos = row_start[erows[e]] + rank[e];
        sorted_cv[pos] = make_int2(ecols[e], __float_as_int(evals[e]));
    }
}

// ---------------------------------------------------------------------------
// Kernel 6: aggregate. One wave per node; bf16x2/lane covers 128 cols.
// Unroll-4: all 4 cv loads + all 4 gathers issued before FMAs (MLP=4).
// out[n] = bias + sum_{e in row n} val_e * support[col_e]
// ---------------------------------------------------------------------------
__global__ __launch_bounds__(256) void gcn_aggregate_csr(const __bf16* __restrict__ support,
                                                         const int2* __restrict__ sorted_cv,
                                                         const int* __restrict__ row_start,
                                                         const float* __restrict__ bias,
                                                         float* __restrict__ out) {
    const int node = (blockIdx.x * 256 + threadIdx.x) >> 6;
    const int lane = threadIdx.x & 63;
    if (node >= N_NODES) return;

    const int beg = row_start[node];
    const int end = row_start[node + 1];

    float2 accA = *(const float2*)&bias[lane * 2];
    float2 accB = make_float2(0.f, 0.f);
    const __bf16* sp = support + lane * 2;

    int i = beg;
    for (; i + 3 < end; i += 4) {
        int2 cv0 = sorted_cv[i];
        int2 cv1 = sorted_cv[i + 1];
        int2 cv2 = sorted_cv[i + 2];
        int2 cv3 = sorted_cv[i + 3];
        bf16x2 s0 = *(const bf16x2*)(sp + (size_t)cv0.x * OUT_F);
        bf16x2 s1 = *(const bf16x2*)(sp + (size_t)cv1.x * OUT_F);
        bf16x2 s2 = *(const bf16x2*)(sp + (size_t)cv2.x * OUT_F);
        bf16x2 s3 = *(const bf16x2*)(sp + (size_t)cv3.x * OUT_F);
        float v0 = __int_as_float(cv0.y);
        float v1 = __int_as_float(cv1.y);
        float v2 = __int_as_float(cv2.y);
        float v3 = __int_as_float(cv3.y);
        accA.x += v0 * (float)s0.x + v1 * (float)s1.x;
        accA.y += v0 * (float)s0.y + v1 * (float)s1.y;
        accB.x += v2 * (float)s2.x + v3 * (float)s3.x;
        accB.y += v2 * (float)s2.y + v3 * (float)s3.y;
    }
    for (; i < end; i++) {
        int2 cv = sorted_cv[i];
        float v = __int_as_float(cv.y);
        bf16x2 s = *(const bf16x2*)(sp + (size_t)cv.x * OUT_F);
        accA.x += v * (float)s.x;
        accA.y += v * (float)s.y;
    }
    accA.x += accB.x;
    accA.y += accB.y;

    *(float2*)&out[(size_t)node * OUT_F + lane * 2] = accA;
}

// ---------------------------------------------------------------------------
static inline size_t align_up(size_t v, size_t a) { return (v + a - 1) & ~(a - 1); }

extern "C" void kernel_launch(void* const* d_in, const int* in_sizes, int n_in,
                              void* d_out, int out_size, void* d_ws, size_t ws_size,
                              hipStream_t stream) {
    const float* x     = (const float*)d_in[0];   // [50000, 256]
    const int*   erows = (const int*)d_in[1];     // [600000]
    const int*   ecols = (const int*)d_in[2];     // [600000]
    const float* evals = (const float*)d_in[3];   // [600000]
    const float* w     = (const float*)d_in[4];   // [256, 128]
    const float* bias  = (const float*)d_in[5];   // [128]
    float* out = (float*)d_out;                   // [50000, 128]

    // workspace layout (all regions 64B-aligned; ~20.7 MB total)
    size_t off = 0;
    __bf16* support   = (__bf16*)((char*)d_ws + off);
    off = align_up(off + (size_t)N_NODES * OUT_F * 2, 64);
    __bf16* wt        = (__bf16*)((char*)d_ws + off);
    off = align_up(off + (size_t)IN_F * OUT_F * 2, 64);
    int*    counts    = (int*)((char*)d_ws + off);
    off = align_up(off + (size_t)N_NODES * 4, 64);
    int*    row_start = (int*)((char*)d_ws + off);
    off = align_up(off + (size_t)(N_NODES + 1) * 4, 64);
    int*    rank      = (int*)((char*)d_ws + off);
    off = align_up(off + (size_t)N_EDGES * 4, 64);
    int*    partials  = (int*)((char*)d_ws + off);
    off = align_up(off + 256 * 4, 64);
    int2*   sorted_cv = (int2*)((char*)d_ws + off);

    const int eblocks = (N_EDGES + 255) / 256;

    // 1) prep: wt transpose + counts zero
    gcn_prep<<<SCAN_BLOCKS, 256, 0, stream>>>(w, wt, counts);

    // 2) GEMM: support = bf16(x @ W)
    gcn_gemm_mfma<<<(N_NODES + 127) / 128, 256, 0, stream>>>(x, wt, support);

    // 3) histogram + rank
    gcn_hist<<<eblocks, 256, 0, stream>>>(erows, counts, rank);

    // 4) exclusive scan: per-block scan + parallel fixup (196 blocks each)
    gcn_scan1<<<SCAN_BLOCKS, 256, 0, stream>>>(counts, row_start, partials);
    gcn_scan_fixup<<<SCAN_BLOCKS, 256, 0, stream>>>(row_start, partials);

    // 5) scatter to row-sorted edge list
    gcn_scatter<<<eblocks, 256, 0, stream>>>(erows, ecols, evals, row_start, rank,
                                             sorted_cv);

    // 6) aggregate + bias (one wave per node, 4 nodes per block)
    gcn_aggregate_csr<<<(N_NODES + 3) / 4, 256, 0, stream>>>(
        support, sorted_cv, row_start, bias, out);
}

// Round 8
// 183.469 us; speedup vs baseline: 1.4947x; 1.0473x over previous
//
#include <hip/hip_runtime.h>
#include <hip/hip_bf16.h>

#define N_NODES 50000
#define N_EDGES 600000
#define IN_F 256
#define OUT_F 128
#define SCAN_BLOCKS 196   // ceil(50000/256)
#define LDS_K (IN_F + 8)  // +8 bf16 (16B) row pad: b128 frag reads hit all 8 bank-groups

typedef __bf16 bf16x8 __attribute__((ext_vector_type(8)));
typedef __bf16 bf16x2 __attribute__((ext_vector_type(2)));
typedef float  f32x4  __attribute__((ext_vector_type(4)));

// ---------------------------------------------------------------------------
// Kernel 1: support = bf16(x @ W) via MFMA 16x16x32.
// 512 threads = 8 waves x 32 rows = 256 rows/block; 196 blocks; 66 KB LDS ->
// 2 blocks/CU = 4 waves/SIMD. W is transposed+converted fp32->bf16 into LDS
// during staging (no separate prep kernel, no wt round-trip). Also zeros
// counts[] for the downstream histogram (stream order guarantees ordering).
// ---------------------------------------------------------------------------
__global__ __launch_bounds__(512) void gcn_gemm_mfma(const float* __restrict__ x,
                                                     const float* __restrict__ w,
                                                     __bf16* __restrict__ support,
                                                     int* __restrict__ counts) {
    __shared__ __bf16 bs[OUT_F * LDS_K];   // 128 * 264 * 2 B = 66 KB

    const int t = threadIdx.x;

    // ---- fused: zero counts (196*512 = 100352 >= 50000) ----
    int gid = blockIdx.x * 512 + t;
    if (gid < N_NODES) counts[gid] = 0;

    // ---- stage W -> LDS transposed + converted: bs[n][k] = bf16(w[k][n]) ----
    // Coalesced global reads; LDS writes are 8-way bank-conflicted scalar b16
    // stores (one-time ~200 cyc/block, negligible vs main loop).
    for (int j = 0; j < 64; j++) {
        int idx = j * 512 + t;        // 0 .. 32767
        int k = idx >> 7;
        int n = idx & 127;
        bs[n * LDS_K + k] = (__bf16)w[idx];
    }
    __syncthreads();

    const int wave = t >> 6;                         // 0..7
    const int lane = t & 63;
    const int m    = lane & 15;
    const int quad = lane >> 4;
    const int row0 = blockIdx.x * 256 + wave * 32;   // this wave: rows row0..row0+31

    int r0 = row0 + m;
    int r1 = row0 + 16 + m;
    const float* xp0 = x + (size_t)(r0 < N_NODES ? r0 : 0) * IN_F + quad * 8;
    const float* xp1 = x + (size_t)(r1 < N_NODES ? r1 : 0) * IN_F + quad * 8;

    f32x4 acc0[8], acc1[8];
#pragma unroll
    for (int nt = 0; nt < 8; nt++) {
        acc0[nt] = (f32x4){0.f, 0.f, 0.f, 0.f};
        acc1[nt] = (f32x4){0.f, 0.f, 0.f, 0.f};
    }

#pragma unroll
    for (int ks = 0; ks < 8; ks++) {
        float4 a00 = *(const float4*)(xp0 + ks * 32);
        float4 a01 = *(const float4*)(xp0 + ks * 32 + 4);
        float4 a10 = *(const float4*)(xp1 + ks * 32);
        float4 a11 = *(const float4*)(xp1 + ks * 32 + 4);
        bf16x8 af0 = { (__bf16)a00.x, (__bf16)a00.y, (__bf16)a00.z, (__bf16)a00.w,
                       (__bf16)a01.x, (__bf16)a01.y, (__bf16)a01.z, (__bf16)a01.w };
        bf16x8 af1 = { (__bf16)a10.x, (__bf16)a10.y, (__bf16)a10.z, (__bf16)a10.w,
                       (__bf16)a11.x, (__bf16)a11.y, (__bf16)a11.z, (__bf16)a11.w };
#pragma unroll
        for (int nt = 0; nt < 8; nt++) {
            bf16x8 bf = *(const bf16x8*)&bs[(nt * 16 + m) * LDS_K + ks * 32 + quad * 8];
            acc0[nt] = __builtin_amdgcn_mfma_f32_16x16x32_bf16(af0, bf, acc0[nt], 0, 0, 0);
            acc1[nt] = __builtin_amdgcn_mfma_f32_16x16x32_bf16(af1, bf, acc1[nt], 0, 0, 0);
        }
    }

    // C/D layout: col = lane&15, row = quad*4 + reg  [m89-verified]
#pragma unroll
    for (int nt = 0; nt < 8; nt++) {
#pragma unroll
        for (int r = 0; r < 4; r++) {
            int ra = row0 + quad * 4 + r;
            if (ra < N_NODES)
                support[(size_t)ra * OUT_F + nt * 16 + m] = (__bf16)acc0[nt][r];
            int rb = ra + 16;
            if (rb < N_NODES)
                support[(size_t)rb * OUT_F + nt * 16 + m] = (__bf16)acc1[nt][r];
        }
    }
}

// ---------------------------------------------------------------------------
// Kernel 2: histogram (+rank per edge)
// ---------------------------------------------------------------------------
__global__ __launch_bounds__(256) void gcn_hist(const int* __restrict__ erows,
                                                int* __restrict__ counts,
                                                int* __restrict__ rank) {
    int e = blockIdx.x * 256 + threadIdx.x;
    if (e < N_EDGES) rank[e] = atomicAdd(&counts[erows[e]], 1);
}

// ---------------------------------------------------------------------------
// Kernel 3: per-block exclusive scan of counts (196 blocks) -> partials
// ---------------------------------------------------------------------------
__global__ __launch_bounds__(256) void gcn_scan1(const int* __restrict__ counts,
                                                 int* __restrict__ row_start,
                                                 int* __restrict__ partials) {
    __shared__ int s[256];
    const int t = threadIdx.x;
    const int i = blockIdx.x * 256 + t;
    int v = (i < N_NODES) ? counts[i] : 0;
    s[t] = v;
    __syncthreads();
#pragma unroll
    for (int off = 1; off < 256; off <<= 1) {
        int x = (t >= off) ? s[t - off] : 0;
        __syncthreads();
        s[t] += x;
        __syncthreads();
    }
    if (i < N_NODES) row_start[i] = s[t] - v;
    if (t == 255) partials[blockIdx.x] = s[255];
}

// ---------------------------------------------------------------------------
// Kernel 4: fixup (196 blocks): every block redundantly scans the 196-entry
// partials (L2-hot) in LDS, then adds its exclusive block-prefix to its span.
// ---------------------------------------------------------------------------
__global__ __launch_bounds__(256) void gcn_scan_fixup(int* __restrict__ row_start,
                                                      const int* __restrict__ partials) {
    __shared__ int s[256];
    const int t = threadIdx.x;
    int v = (t < SCAN_BLOCKS) ? partials[t] : 0;
    s[t] = v;
    __syncthreads();
#pragma unroll
    for (int off = 1; off < 256; off <<= 1) {
        int x = (t >= off) ? s[t - off] : 0;
        __syncthreads();
        s[t] += x;
        __syncthreads();
    }
    const int add = (blockIdx.x == 0) ? 0 : s[blockIdx.x - 1];
    const int i = blockIdx.x * 256 + t;
    if (i < N_NODES) row_start[i] += add;
    if (i == 0) row_start[N_NODES] = N_EDGES;
}

// ---------------------------------------------------------------------------
// Kernel 5: packed scatter into row-sorted edge list
// ---------------------------------------------------------------------------
__global__ __launch_bounds__(256) void gcn_scatter(const int* __restrict__ erows,
                                                   const int* __restrict__ ecols,
                                                   const float* __restrict__ evals,
                                                   const int* __restrict__ row_start,
                                                   const int* __restrict__ rank,
                                                   int2* __restrict__ sorted_cv) {
    int e = blockIdx.x * 256 + threadIdx.x;
    if (e < N_EDGES) {
        int pos = row_start[erows[e]] + rank[e];
        sorted_cv[pos] = make_int2(ecols[e], __float_as_int(evals[e]));
    }
}

// ---------------------------------------------------------------------------
// Kernel 6: aggregate. One wave per node; bf16x2/lane covers 128 cols.
// Unroll-8: all 8 cv broadcasts + all 8 row gathers in flight before FMAs.
// out[n] = bias + sum_{e in row n} val_e * support[col_e]
// ---------------------------------------------------------------------------
__global__ __launch_bounds__(256) void gcn_aggregate_csr(const __bf16* __restrict__ support,
                                                         const int2* __restrict__ sorted_cv,
                                                         const int* __restrict__ row_start,
                                                         const float* __restrict__ bias,
                                                         float* __restrict__ out) {
    const int node = (blockIdx.x * 256 + threadIdx.x) >> 6;
    const int lane = threadIdx.x & 63;
    if (node >= N_NODES) return;

    const int beg = row_start[node];
    const int end = row_start[node + 1];

    float2 accA = *(const float2*)&bias[lane * 2];
    float2 accB = make_float2(0.f, 0.f);
    const __bf16* sp = support + lane * 2;

    int i = beg;
    for (; i + 7 < end; i += 8) {
        int2 cv0 = sorted_cv[i];
        int2 cv1 = sorted_cv[i + 1];
        int2 cv2 = sorted_cv[i + 2];
        int2 cv3 = sorted_cv[i + 3];
        int2 cv4 = sorted_cv[i + 4];
        int2 cv5 = sorted_cv[i + 5];
        int2 cv6 = sorted_cv[i + 6];
        int2 cv7 = sorted_cv[i + 7];
        bf16x2 s0 = *(const bf16x2*)(sp + (size_t)cv0.x * OUT_F);
        bf16x2 s1 = *(const bf16x2*)(sp + (size_t)cv1.x * OUT_F);
        bf16x2 s2 = *(const bf16x2*)(sp + (size_t)cv2.x * OUT_F);
        bf16x2 s3 = *(const bf16x2*)(sp + (size_t)cv3.x * OUT_F);
        bf16x2 s4 = *(const bf16x2*)(sp + (size_t)cv4.x * OUT_F);
        bf16x2 s5 = *(const bf16x2*)(sp + (size_t)cv5.x * OUT_F);
        bf16x2 s6 = *(const bf16x2*)(sp + (size_t)cv6.x * OUT_F);
        bf16x2 s7 = *(const bf16x2*)(sp + (size_t)cv7.x * OUT_F);
        accA.x += __int_as_float(cv0.y) * (float)s0.x + __int_as_float(cv1.y) * (float)s1.x;
        accA.y += __int_as_float(cv0.y) * (float)s0.y + __int_as_float(cv1.y) * (float)s1.y;
        accB.x += __int_as_float(cv2.y) * (float)s2.x + __int_as_float(cv3.y) * (float)s3.x;
        accB.y += __int_as_float(cv2.y) * (float)s2.y + __int_as_float(cv3.y) * (float)s3.y;
        accA.x += __int_as_float(cv4.y) * (float)s4.x + __int_as_float(cv5.y) * (float)s5.x;
        accA.y += __int_as_float(cv4.y) * (float)s4.y + __int_as_float(cv5.y) * (float)s5.y;
        accB.x += __int_as_float(cv6.y) * (float)s6.x + __int_as_float(cv7.y) * (float)s7.x;
        accB.y += __int_as_float(cv6.y) * (float)s6.y + __int_as_float(cv7.y) * (float)s7.y;
    }
    for (; i + 3 < end; i += 4) {
        int2 cv0 = sorted_cv[i];
        int2 cv1 = sorted_cv[i + 1];
        int2 cv2 = sorted_cv[i + 2];
        int2 cv3 = sorted_cv[i + 3];
        bf16x2 s0 = *(const bf16x2*)(sp + (size_t)cv0.x * OUT_F);
        bf16x2 s1 = *(const bf16x2*)(sp + (size_t)cv1.x * OUT_F);
        bf16x2 s2 = *(const bf16x2*)(sp + (size_t)cv2.x * OUT_F);
        bf16x2 s3 = *(const bf16x2*)(sp + (size_t)cv3.x * OUT_F);
        accA.x += __int_as_float(cv0.y) * (float)s0.x + __int_as_float(cv1.y) * (float)s1.x;
        accA.y += __int_as_float(cv0.y) * (float)s0.y + __int_as_float(cv1.y) * (float)s1.y;
        accB.x += __int_as_float(cv2.y) * (float)s2.x + __int_as_float(cv3.y) * (float)s3.x;
        accB.y += __int_as_float(cv2.y) * (float)s2.y + __int_as_float(cv3.y) * (float)s3.y;
    }
    for (; i < end; i++) {
        int2 cv = sorted_cv[i];
        float v = __int_as_float(cv.y);
        bf16x2 s = *(const bf16x2*)(sp + (size_t)cv.x * OUT_F);
        accA.x += v * (float)s.x;
        accA.y += v * (float)s.y;
    }
    accA.x += accB.x;
    accA.y += accB.y;

    *(float2*)&out[(size_t)node * OUT_F + lane * 2] = accA;
}

// ---------------------------------------------------------------------------
static inline size_t align_up(size_t v, size_t a) { return (v + a - 1) & ~(a - 1); }

extern "C" void kernel_launch(void* const* d_in, const int* in_sizes, int n_in,
                              void* d_out, int out_size, void* d_ws, size_t ws_size,
                              hipStream_t stream) {
    const float* x     = (const float*)d_in[0];   // [50000, 256]
    const int*   erows = (const int*)d_in[1];     // [600000]
    const int*   ecols = (const int*)d_in[2];     // [600000]
    const float* evals = (const float*)d_in[3];   // [600000]
    const float* w     = (const float*)d_in[4];   // [256, 128]
    const float* bias  = (const float*)d_in[5];   // [128]
    float* out = (float*)d_out;                   // [50000, 128]

    // workspace layout (all regions 64B-aligned; ~20.6 MB total)
    size_t off = 0;
    __bf16* support   = (__bf16*)((char*)d_ws + off);
    off = align_up(off + (size_t)N_NODES * OUT_F * 2, 64);
    int*    counts    = (int*)((char*)d_ws + off);
    off = align_up(off + (size_t)N_NODES * 4, 64);
    int*    row_start = (int*)((char*)d_ws + off);
    off = align_up(off + (size_t)(N_NODES + 1) * 4, 64);
    int*    rank      = (int*)((char*)d_ws + off);
    off = align_up(off + (size_t)N_EDGES * 4, 64);
    int*    partials  = (int*)((char*)d_ws + off);
    off = align_up(off + 256 * 4, 64);
    int2*   sorted_cv = (int2*)((char*)d_ws + off);

    const int eblocks = (N_EDGES + 255) / 256;

    // 1) GEMM (fused: W transpose->LDS, counts zeroing): support = bf16(x @ W)
    gcn_gemm_mfma<<<SCAN_BLOCKS, 512, 0, stream>>>(x, w, support, counts);

    // 2) histogram + rank
    gcn_hist<<<eblocks, 256, 0, stream>>>(erows, counts, rank);

    // 3) exclusive scan: per-block scan + parallel fixup (196 blocks each)
    gcn_scan1<<<SCAN_BLOCKS, 256, 0, stream>>>(counts, row_start, partials);
    gcn_scan_fixup<<<SCAN_BLOCKS, 256, 0, stream>>>(row_start, partials);

    // 4) scatter to row-sorted edge list
    gcn_scatter<<<eblocks, 256, 0, stream>>>(erows, ecols, evals, row_start, rank,
                                             sorted_cv);

    // 5) aggregate + bias (one wave per node, 4 nodes per block)
    gcn_aggregate_csr<<<(N_NODES + 3) / 4, 256, 0, stream>>>(
        support, sorted_cv, row_start, bias, out);
}

// Round 9
// 173.480 us; speedup vs baseline: 1.5808x; 1.0576x over previous
//
#include <hip/hip_runtime.h>
#include <hip/hip_bf16.h>

#define N_NODES 50000
#define N_EDGES 600000
#define IN_F 256
#define OUT_F 128
#define SCAN_BLOCKS 196    // ceil(50000/256)
#define GEMM_BLOCKS 196    // ceil(50000/256) rows, 256 rows per block
#define HIST_BLOCKS 1172   // ceil(600000/512)
#define LDS_K (IN_F + 8)   // +8 bf16 (16B) row pad: b128 frag reads hit all 8 bank-groups

typedef __bf16 bf16x8 __attribute__((ext_vector_type(8)));
typedef __bf16 bf16x2 __attribute__((ext_vector_type(2)));
typedef float  f32x4  __attribute__((ext_vector_type(4)));

// ---------------------------------------------------------------------------
// Kernel 1 (fused): blocks [0,196) = GEMM  support = bf16(x @ W);
//                   blocks [196,1368) = histogram rank[e] = counts[erows[e]]++.
// The two workloads are independent; hist backfills CUs the 196-block GEMM
// leaves idle (kernel time = max, not sum). counts[] zeroed by a prior
// hipMemsetAsync on the stream.
// GEMM: 512 thr = 8 waves x 32 rows; W transposed fp32->bf16 into 66 KB LDS.
// ---------------------------------------------------------------------------
__global__ __launch_bounds__(512) void gcn_gemm_hist(const float* __restrict__ x,
                                                     const float* __restrict__ w,
                                                     __bf16* __restrict__ support,
                                                     const int* __restrict__ erows,
                                                     int* __restrict__ counts,
                                                     int* __restrict__ rank) {
    const int t = threadIdx.x;

    if (blockIdx.x >= GEMM_BLOCKS) {
        // ---------------- histogram part ----------------
        int e = (blockIdx.x - GEMM_BLOCKS) * 512 + t;
        if (e < N_EDGES) rank[e] = atomicAdd(&counts[erows[e]], 1);
        return;
    }

    // ---------------- GEMM part ----------------
    __shared__ __bf16 bs[OUT_F * LDS_K];   // 128 * 264 * 2 B = 66 KB

    // stage W -> LDS transposed + converted: bs[n][k] = bf16(w[k][n])
    for (int j = 0; j < 64; j++) {
        int idx = j * 512 + t;        // 0 .. 32767
        int k = idx >> 7;
        int n = idx & 127;
        bs[n * LDS_K + k] = (__bf16)w[idx];
    }
    __syncthreads();

    const int wave = t >> 6;                         // 0..7
    const int lane = t & 63;
    const int m    = lane & 15;
    const int quad = lane >> 4;
    const int row0 = blockIdx.x * 256 + wave * 32;   // this wave: rows row0..row0+31

    int r0 = row0 + m;
    int r1 = row0 + 16 + m;
    const float* xp0 = x + (size_t)(r0 < N_NODES ? r0 : 0) * IN_F + quad * 8;
    const float* xp1 = x + (size_t)(r1 < N_NODES ? r1 : 0) * IN_F + quad * 8;

    f32x4 acc0[8], acc1[8];
#pragma unroll
    for (int nt = 0; nt < 8; nt++) {
        acc0[nt] = (f32x4){0.f, 0.f, 0.f, 0.f};
        acc1[nt] = (f32x4){0.f, 0.f, 0.f, 0.f};
    }

#pragma unroll
    for (int ks = 0; ks < 8; ks++) {
        float4 a00 = *(const float4*)(xp0 + ks * 32);
        float4 a01 = *(const float4*)(xp0 + ks * 32 + 4);
        float4 a10 = *(const float4*)(xp1 + ks * 32);
        float4 a11 = *(const float4*)(xp1 + ks * 32 + 4);
        bf16x8 af0 = { (__bf16)a00.x, (__bf16)a00.y, (__bf16)a00.z, (__bf16)a00.w,
                       (__bf16)a01.x, (__bf16)a01.y, (__bf16)a01.z, (__bf16)a01.w };
        bf16x8 af1 = { (__bf16)a10.x, (__bf16)a10.y, (__bf16)a10.z, (__bf16)a10.w,
                       (__bf16)a11.x, (__bf16)a11.y, (__bf16)a11.z, (__bf16)a11.w };
#pragma unroll
        for (int nt = 0; nt < 8; nt++) {
            bf16x8 bf = *(const bf16x8*)&bs[(nt * 16 + m) * LDS_K + ks * 32 + quad * 8];
            acc0[nt] = __builtin_amdgcn_mfma_f32_16x16x32_bf16(af0, bf, acc0[nt], 0, 0, 0);
            acc1[nt] = __builtin_amdgcn_mfma_f32_16x16x32_bf16(af1, bf, acc1[nt], 0, 0, 0);
        }
    }

    // C/D layout: col = lane&15, row = quad*4 + reg  [m89-verified]
#pragma unroll
    for (int nt = 0; nt < 8; nt++) {
#pragma unroll
        for (int r = 0; r < 4; r++) {
            int ra = row0 + quad * 4 + r;
            if (ra < N_NODES)
                support[(size_t)ra * OUT_F + nt * 16 + m] = (__bf16)acc0[nt][r];
            int rb = ra + 16;
            if (rb < N_NODES)
                support[(size_t)rb * OUT_F + nt * 16 + m] = (__bf16)acc1[nt][r];
        }
    }
}

// ---------------------------------------------------------------------------
// Kernel 2: per-block exclusive scan of counts (196 blocks) -> block-local
// row_start + per-block totals in partials. (No global fixup pass: consumers
// reconstruct absolute offsets from partials themselves.)
// ---------------------------------------------------------------------------
__global__ __launch_bounds__(256) void gcn_scan1(const int* __restrict__ counts,
                                                 int* __restrict__ row_start,
                                                 int* __restrict__ partials) {
    __shared__ int s[256];
    const int t = threadIdx.x;
    const int i = blockIdx.x * 256 + t;
    int v = (i < N_NODES) ? counts[i] : 0;
    s[t] = v;
    __syncthreads();
#pragma unroll
    for (int off = 1; off < 256; off <<= 1) {
        int x = (t >= off) ? s[t - off] : 0;
        __syncthreads();
        s[t] += x;
        __syncthreads();
    }
    if (i < N_NODES) row_start[i] = s[t] - v;     // block-local exclusive
    if (t == 255) partials[blockIdx.x] = s[255];
}

// ---------------------------------------------------------------------------
// Kernel 3: packed scatter. Each block redundantly scans the 196-entry
// partials in LDS (L2-hot, ~0.2us), then pos = local_rs + block_pref + rank.
// ---------------------------------------------------------------------------
__global__ __launch_bounds__(256) void gcn_scatter(const int* __restrict__ erows,
                                                   const int* __restrict__ ecols,
                                                   const float* __restrict__ evals,
                                                   const int* __restrict__ row_start,
                                                   const int* __restrict__ rank,
                                                   const int* __restrict__ partials,
                                                   int2* __restrict__ sorted_cv) {
    __shared__ int s[256];
    const int t = threadIdx.x;
    int v = (t < SCAN_BLOCKS) ? partials[t] : 0;
    s[t] = v;
    __syncthreads();
#pragma unroll
    for (int off = 1; off < 256; off <<= 1) {
        int x = (t >= off) ? s[t - off] : 0;
        __syncthreads();
        s[t] += x;
        __syncthreads();
    }
    int e = blockIdx.x * 256 + t;
    if (e < N_EDGES) {
        int r = erows[e];
        int blk = r >> 8;
        int add = blk ? s[blk - 1] : 0;
        int pos = row_start[r] + add + rank[e];
        sorted_cv[pos] = make_int2(ecols[e], __float_as_int(evals[e]));
    }
}

// ---------------------------------------------------------------------------
// Kernel 4: aggregate. One wave per node; bf16x2/lane covers 128 cols.
// Per-block partials scan reconstructs absolute beg/end. Unroll-8 (MLP=8).
// out[n] = bias + sum_{e in row n} val_e * support[col_e]
// ---------------------------------------------------------------------------
__global__ __launch_bounds__(256) void gcn_aggregate_csr(const __bf16* __restrict__ support,
                                                         const int2* __restrict__ sorted_cv,
                                                         const int* __restrict__ row_start,
                                                         const int* __restrict__ partials,
                                                         const float* __restrict__ bias,
                                                         float* __restrict__ out) {
    __shared__ int s[256];
    const int t = threadIdx.x;
    int pv = (t < SCAN_BLOCKS) ? partials[t] : 0;
    s[t] = pv;
    __syncthreads();
#pragma unroll
    for (int off = 1; off < 256; off <<= 1) {
        int x = (t >= off) ? s[t - off] : 0;
        __syncthreads();
        s[t] += x;
        __syncthreads();
    }

    const int node = (blockIdx.x * 256 + t) >> 6;
    const int lane = t & 63;
    if (node >= N_NODES) return;

    int blk = node >> 8;
    const int beg = row_start[node] + (blk ? s[blk - 1] : 0);
    int end;
    if (node + 1 < N_NODES) {
        int blk1 = (node + 1) >> 8;
        end = row_start[node + 1] + (blk1 ? s[blk1 - 1] : 0);
    } else {
        end = N_EDGES;
    }

    float2 accA = *(const float2*)&bias[lane * 2];
    float2 accB = make_float2(0.f, 0.f);
    const __bf16* sp = support + lane * 2;

    int i = beg;
    for (; i + 7 < end; i += 8) {
        int2 cv0 = sorted_cv[i];
        int2 cv1 = sorted_cv[i + 1];
        int2 cv2 = sorted_cv[i + 2];
        int2 cv3 = sorted_cv[i + 3];
        int2 cv4 = sorted_cv[i + 4];
        int2 cv5 = sorted_cv[i + 5];
        int2 cv6 = sorted_cv[i + 6];
        int2 cv7 = sorted_cv[i + 7];
        bf16x2 s0 = *(const bf16x2*)(sp + (size_t)cv0.x * OUT_F);
        bf16x2 s1 = *(const bf16x2*)(sp + (size_t)cv1.x * OUT_F);
        bf16x2 s2 = *(const bf16x2*)(sp + (size_t)cv2.x * OUT_F);
        bf16x2 s3 = *(const bf16x2*)(sp + (size_t)cv3.x * OUT_F);
        bf16x2 s4 = *(const bf16x2*)(sp + (size_t)cv4.x * OUT_F);
        bf16x2 s5 = *(const bf16x2*)(sp + (size_t)cv5.x * OUT_F);
        bf16x2 s6 = *(const bf16x2*)(sp + (size_t)cv6.x * OUT_F);
        bf16x2 s7 = *(const bf16x2*)(sp + (size_t)cv7.x * OUT_F);
        accA.x += __int_as_float(cv0.y) * (float)s0.x + __int_as_float(cv1.y) * (float)s1.x;
        accA.y += __int_as_float(cv0.y) * (float)s0.y + __int_as_float(cv1.y) * (float)s1.y;
        accB.x += __int_as_float(cv2.y) * (float)s2.x + __int_as_float(cv3.y) * (float)s3.x;
        accB.y += __int_as_float(cv2.y) * (float)s2.y + __int_as_float(cv3.y) * (float)s3.y;
        accA.x += __int_as_float(cv4.y) * (float)s4.x + __int_as_float(cv5.y) * (float)s5.x;
        accA.y += __int_as_float(cv4.y) * (float)s4.y + __int_as_float(cv5.y) * (float)s5.y;
        accB.x += __int_as_float(cv6.y) * (float)s6.x + __int_as_float(cv7.y) * (float)s7.x;
        accB.y += __int_as_float(cv6.y) * (float)s6.y + __int_as_float(cv7.y) * (float)s7.y;
    }
    for (; i + 3 < end; i += 4) {
        int2 cv0 = sorted_cv[i];
        int2 cv1 = sorted_cv[i + 1];
        int2 cv2 = sorted_cv[i + 2];
        int2 cv3 = sorted_cv[i + 3];
        bf16x2 s0 = *(const bf16x2*)(sp + (size_t)cv0.x * OUT_F);
        bf16x2 s1 = *(const bf16x2*)(sp + (size_t)cv1.x * OUT_F);
        bf16x2 s2 = *(const bf16x2*)(sp + (size_t)cv2.x * OUT_F);
        bf16x2 s3 = *(const bf16x2*)(sp + (size_t)cv3.x * OUT_F);
        accA.x += __int_as_float(cv0.y) * (float)s0.x + __int_as_float(cv1.y) * (float)s1.x;
        accA.y += __int_as_float(cv0.y) * (float)s0.y + __int_as_float(cv1.y) * (float)s1.y;
        accB.x += __int_as_float(cv2.y) * (float)s2.x + __int_as_float(cv3.y) * (float)s3.x;
        accB.y += __int_as_float(cv2.y) * (float)s2.y + __int_as_float(cv3.y) * (float)s3.y;
    }
    for (; i < end; i++) {
        int2 cv = sorted_cv[i];
        float v = __int_as_float(cv.y);
        bf16x2 sv = *(const bf16x2*)(sp + (size_t)cv.x * OUT_F);
        accA.x += v * (float)sv.x;
        accA.y += v * (float)sv.y;
    }
    accA.x += accB.x;
    accA.y += accB.y;

    *(float2*)&out[(size_t)node * OUT_F + lane * 2] = accA;
}

// ---------------------------------------------------------------------------
static inline size_t align_up(size_t v, size_t a) { return (v + a - 1) & ~(a - 1); }

extern "C" void kernel_launch(void* const* d_in, const int* in_sizes, int n_in,
                              void* d_out, int out_size, void* d_ws, size_t ws_size,
                              hipStream_t stream) {
    const float* x     = (const float*)d_in[0];   // [50000, 256]
    const int*   erows = (const int*)d_in[1];     // [600000]
    const int*   ecols = (const int*)d_in[2];     // [600000]
    const float* evals = (const float*)d_in[3];   // [600000]
    const float* w     = (const float*)d_in[4];   // [256, 128]
    const float* bias  = (const float*)d_in[5];   // [128]
    float* out = (float*)d_out;                   // [50000, 128]

    // workspace layout (all regions 64B-aligned; ~20.6 MB total)
    size_t off = 0;
    __bf16* support   = (__bf16*)((char*)d_ws + off);
    off = align_up(off + (size_t)N_NODES * OUT_F * 2, 64);
    int*    counts    = (int*)((char*)d_ws + off);
    off = align_up(off + (size_t)N_NODES * 4, 64);
    int*    row_start = (int*)((char*)d_ws + off);
    off = align_up(off + (size_t)N_NODES * 4, 64);
    int*    rank      = (int*)((char*)d_ws + off);
    off = align_up(off + (size_t)N_EDGES * 4, 64);
    int*    partials  = (int*)((char*)d_ws + off);
    off = align_up(off + 256 * 4, 64);
    int2*   sorted_cv = (int2*)((char*)d_ws + off);

    const int eblocks = (N_EDGES + 255) / 256;

    // 0) zero histogram counters (stream-ordered, graph-capturable)
    hipMemsetAsync(counts, 0, (size_t)N_NODES * 4, stream);

    // 1) fused GEMM + histogram (independent workloads co-scheduled)
    gcn_gemm_hist<<<GEMM_BLOCKS + HIST_BLOCKS, 512, 0, stream>>>(
        x, w, support, erows, counts, rank);

    // 2) block-local exclusive scan -> row_start, partials
    gcn_scan1<<<SCAN_BLOCKS, 256, 0, stream>>>(counts, row_start, partials);

    // 3) scatter to row-sorted edge list (absolute pos via in-block partials scan)
    gcn_scatter<<<eblocks, 256, 0, stream>>>(erows, ecols, evals, row_start, rank,
                                             partials, sorted_cv);

    // 4) aggregate + bias (one wave per node; absolute beg/end via partials scan)
    gcn_aggregate_csr<<<(N_NODES + 3) / 4, 256, 0, stream>>>(
        support, sorted_cv, row_start, partials, bias, out);
}